// Round 11
// baseline (45.155 us; speedup 1.0000x reference)
//
#include <hip/hip_runtime.h>
#include <math.h>

#define K_TOP 16
#define D_DIM 1024
#define N_ROWS 2048                       // 32 * 64 rows

typedef float f32x4 __attribute__((ext_vector_type(4)));

// One block (320 thr = 5 waves) per row q.
//   waves 0..3 (writers): zero k-rows wave*4..wave*4+3 (16 x 1KB f32x4
//     stores, issued from cycle ~0; 100% of store traffic is early and
//     4-wave balanced). Then spin on an LDS flag, drain OWN stores
//     (per-wave vmcnt(0), no block-wide barrier), and lanes 0..3 write
//     the 1.0 for their own 4 k-rows.
//   wave 4 (selector): loads logits[r]+gn[q] (f32x4, lane owns
//     d=lane*16+j), 16 rounds of {per-lane masked argmax -> 64-lane
//     butterfly argmax} (tie-break smaller index), rank-sorts ascending,
//     publishes sel[16] to LDS, sets flag. No global stores.
// No __syncthreads after stores -> no block-wide vmcnt(0) drain.
__global__ __launch_bounds__(320) void dps_topk_kernel(
    const float* __restrict__ logits,  // (64, 1024)
    const float* __restrict__ gn,      // (32, 64, 1024)
    float* __restrict__ out)           // (32, 64, 16, 1024)
{
    const int tid  = threadIdx.x;
    const int lane = tid & 63;
    const int wave = tid >> 6;          // 0..4
    const int q    = blockIdx.x;
    const int r    = q & 63;

    __shared__ volatile int sel_lds[K_TOP];
    __shared__ volatile int flag;

    if (tid == 0) flag = 0;
    __syncthreads();   // entry barrier: no vmem outstanding yet, cheap

    float* orow = out + (size_t)q * (K_TOP * D_DIM);
    f32x4* o4   = reinterpret_cast<f32x4*>(orow);

    if (wave < 4) {
        // ---- zero own 4 k-rows immediately: 16 x 1KB stores ----
        const f32x4 z = {0.f, 0.f, 0.f, 0.f};
        f32x4* base = o4 + wave * 1024 + lane;
        #pragma unroll
        for (int i = 0; i < 16; ++i) base[i * 64] = z;
        asm volatile("" ::: "memory");   // keep stores above the spin

        // ---- wait for the selector's result ----
        while (flag == 0) { __builtin_amdgcn_s_sleep(2); }

        // ---- order own one-stores after own zero-stores ----
        asm volatile("s_waitcnt vmcnt(0)" ::: "memory");
        if (lane < 4) {
            const int k = wave * 4 + lane;
            const int s = sel_lds[k];
            orow[k * D_DIM + s] = 1.0f;
        }
    } else {
        // ---- selector: load + perturb (lane owns 16 consecutive) ----
        float v[16];
        {
            const f32x4* l4 = reinterpret_cast<const f32x4*>(
                logits + (size_t)r * D_DIM + lane * 16);
            const f32x4* g4 = reinterpret_cast<const f32x4*>(
                gn + (size_t)q * D_DIM + lane * 16);
            #pragma unroll
            for (int c = 0; c < 4; ++c) {
                const f32x4 a = l4[c];
                const f32x4 b = g4[c];
                v[c * 4 + 0] = a.x + b.x;
                v[c * 4 + 1] = a.y + b.y;
                v[c * 4 + 2] = a.z + b.z;
                v[c * 4 + 3] = a.w + b.w;
            }
        }

        // ---- 16 rounds of wave-wide argmax ----
        unsigned chosen = 0;
        int my_sel = 0;
        for (int round = 0; round < K_TOP; ++round) {
            float bv = -INFINITY;
            int   bi = 0x7fffffff;
            #pragma unroll
            for (int j = 0; j < 16; ++j) {
                if (!(chosen & (1u << j))) {
                    // strict > keeps smaller j (= smaller index) on ties
                    if (v[j] > bv) { bv = v[j]; bi = lane * 16 + j; }
                }
            }
            #pragma unroll
            for (int off = 32; off > 0; off >>= 1) {
                const float ov = __shfl_xor(bv, off);
                const int   oi = __shfl_xor(bi, off);
                if (ov > bv || (ov == bv && oi < bi)) { bv = ov; bi = oi; }
            }
            if (lane == (bi >> 4)) chosen |= 1u << (bi & 15);
            if (lane == round)     my_sel = bi;
        }

        // ---- rank among the 16 winners = ascending index order ----
        int rank = 0;
        #pragma unroll
        for (int j = 0; j < K_TOP; ++j) {
            const int other = __shfl(my_sel, j);
            rank += (other < my_sel) ? 1 : 0;
        }

        // ---- publish selection, then release the writers ----
        if (lane < K_TOP) sel_lds[rank] = my_sel;
        __threadfence_block();           // LDS writes visible block-wide
        if (lane == 0) flag = 1;
    }
}

extern "C" void kernel_launch(void* const* d_in, const int* in_sizes, int n_in,
                              void* d_out, int out_size, void* d_ws, size_t ws_size,
                              hipStream_t stream) {
    const float* logits = (const float*)d_in[0];  // (64, 1024) f32
    const float* gn     = (const float*)d_in[1];  // (32, 64, 1024) f32
    float* out          = (float*)d_out;          // (32, 64, 16, 1024) f32

    dps_topk_kernel<<<dim3(N_ROWS), dim3(320), 0, stream>>>(logits, gn, out);
}